// Round 19
// baseline (153.742 us; speedup 1.0000x reference)
//
#include <hip/hip_runtime.h>
#include <hip/hip_bf16.h>
#include <math.h>

#define HH 128
#define WW 128
#define HWSZ 16384

typedef __attribute__((ext_vector_type(8))) short short8;
typedef __attribute__((ext_vector_type(4))) float f32x4;

// ---- workspace layout (bytes) ----
constexpr int OFF_CATT  = 0;           // 8,388,608  [pix][128] bf16: nbr@0, ref@64
constexpr int OFF_CAT2T = 8388608;     // 8,388,608  [pix][128] bf16: agg@0, ref@64
constexpr int OFF_WF1   = 16777216;    // 4,194,304  [pix][64] bf16
constexpr int OFF_WF2   = 20971520;    // 4,194,304
constexpr int OFF_MASK  = 25165824;    // 9,437,184  [pix][72] fp32
constexpr int OFF_IDX   = 34603008;    //   524,288  [pix] int4 packed ph|pw<<16
constexpr int OFF_WT1   = 35127296;    //   147,456  [64][1152] bf16
constexpr int OFF_WT2   = 35274752;    //    73,728  [64][576]
constexpr int OFF_WTM   = 35348480;    //   110,592  [96][576] (rows>=72 zero)
constexpr int OFF_WTA   = 35495936;    //   147,456  [64][1152]
constexpr int OFF_ZROW  = 35643392;    //       256  zeros (OOB gather target)
constexpr int OFF_WB    = 35644416;    //   294,912  [4][576][64] bf16 plain
constexpr int OFF_F1T   = 38797312;    // 8,388,608  fp32 c4-chunked [b][16][hw][4]
constexpr int OFF_F2T   = 47185920;    // 8,388,608
constexpr int OFF_D     = 55574528;    // 15,859,712 (dead after topk_s1)
constexpr int OFF_PV    = 71434240;    // 5,767,168  float4 [11][32768]
constexpr int OFF_PP    = 77201408;    // 5,767,168  int4   [11][32768]

__device__ inline ushort f2bf(float f) {
    __hip_bfloat16 h = __float2bfloat16(f);
    return *reinterpret_cast<ushort*>(&h);
}
__device__ inline float bf2f(ushort u) {
    return __uint_as_float(((unsigned)u) << 16);
}

// async global->LDS, 16B per lane; LDS dest = wave-uniform base + lane*16
__device__ inline void gload16(const void* g, void* l) {
    __builtin_amdgcn_global_load_lds(
        (const __attribute__((address_space(1))) unsigned int*)g,
        (__attribute__((address_space(3))) unsigned int*)l, 16, 0, 0);
}

// ---------------- l2norm+transpose body ----------------
__device__ void l2t2_body(int bid, const float* __restrict__ in,
                          float4* __restrict__ normT4,
                          ushort* __restrict__ d1, ushort* __restrict__ d2)
{
    const int pix0 = bid * 64;
    const int b = pix0 >> 14;
    const int hw0 = pix0 & (HWSZ - 1);
    __shared__ float s[64][65];
    __shared__ float sinv[64];
    const int tid = threadIdx.x;
    {
        const int p = tid & 63, c4 = tid >> 6;
#pragma unroll
        for (int r = 0; r < 16; ++r) {
            int c = r * 4 + c4;
            s[c][p] = in[(((size_t)b * 64 + c) << 14) + hw0 + p];
        }
    }
    __syncthreads();
    if (tid < 64) {
        float sum = 0.f;
#pragma unroll
        for (int c = 0; c < 64; ++c) { float v = s[c][tid]; sum = fmaf(v, v, sum); }
        sinv[tid] = 1.f / fmaxf(sqrtf(sum), 1e-12f);
    }
    __syncthreads();
    {
        const int pp = tid & 63, cg = tid >> 6;
        const float inv = sinv[pp];
#pragma unroll
        for (int r = 0; r < 4; ++r) {
            int c4 = cg * 4 + r;
            float4 v = make_float4(s[c4 * 4 + 0][pp] * inv, s[c4 * 4 + 1][pp] * inv,
                                   s[c4 * 4 + 2][pp] * inv, s[c4 * 4 + 3][pp] * inv);
            normT4[(((size_t)b * 16 + c4) << 14) + hw0 + pp] = v;
        }
    }
    {
        const int c = tid & 63, p4 = tid >> 6;
#pragma unroll
        for (int r = 0; r < 16; ++r) {
            int pp = r * 4 + p4;
            ushort bv = f2bf(s[c][pp]);
            d1[(size_t)(pix0 + pp) * 128 + c] = bv;
            if (d2) d2[(size_t)(pix0 + pp) * 128 + c] = bv;
        }
    }
}

// ---------------- fused weight prep body ----------------
__device__ inline ushort wt_elem(const float* __restrict__ w, int Cin, int Cout, int idx) {
    int kc = 9 * Cin;
    int o = idx / kc, rem = idx % kc;
    int tap = rem / Cin, c = rem % Cin;
    float val = (o < Cout) ? w[((size_t)o * Cin + c) * 9 + tap] : 0.f;
    return f2bf(val);
}

__device__ void prep_body(int bid,
                          const float* __restrict__ c1w, const float* __restrict__ c2w,
                          const float* __restrict__ mw,  const float* __restrict__ aw,
                          const float* __restrict__ nnw, char* __restrict__ W)
{
    int gid = bid * 256 + threadIdx.x;   // 387200 total
    if (gid < 73728) {
        ((ushort*)(W + OFF_WT1))[gid] = wt_elem(c1w, 128, 64, gid);
    } else if (gid < 110592) {
        int i = gid - 73728;
        ((ushort*)(W + OFF_WT2))[i] = wt_elem(c2w, 64, 64, i);
    } else if (gid < 165888) {
        int i = gid - 110592;
        ((ushort*)(W + OFF_WTM))[i] = wt_elem(mw, 64, 72, i);
    } else if (gid < 239616) {
        int i = gid - 165888;
        ((ushort*)(W + OFF_WTA))[i] = wt_elem(aw, 128, 64, i);
    } else if (gid < 387072) {
        int idx = gid - 239616;
        int j = idx / 36864, rem = idx % 36864;
        int rb = rem >> 6, c = rem & 63;
        int e = rb >> 6, o = rb & 63;
        int ky = e / 3, kx = e % 3;
        ((ushort*)(W + OFF_WB))[idx] =
            f2bf(nnw[(((size_t)o * 256 + j * 64 + c) * 3 + ky) * 3 + kx]);
    } else if (gid < 387200) {
        ((ushort*)(W + OFF_ZROW))[gid - 387072] = 0;
    }
}

// ---------------- dots via LDS-staged f2 rows (2 rows, 8-c4 chunks) ----------------
__device__ void dot_body(int bid, const float4* __restrict__ f1t4,
                         const float4* __restrict__ f2t4, float* __restrict__ D,
                         const char* __restrict__ zrow, char* __restrict__ sF)
{
    const int q  = bid / 128;
    const int rr = bid % 128;
    const int b  = rr >> 6;
    const int hp = rr & 63;
    const int tid = threadIdx.x;
    const int w = tid & 127, rloc = tid >> 7;
    const int wv = tid >> 6;
    const int h = hp * 2 + rloc;
    const int hw = (h << 7) + w;
    const int y = h + q - 5;
    const bool yok = (unsigned)y < (unsigned)HH;

    float acc[11] = {};
    const float4* f1p = f1t4 + (((size_t)b * 16) << 14) + hw;
    const float4* f2row = f2t4 + (((size_t)b * 16) << 14) + (y << 7) + w;

#pragma unroll 1
    for (int ch = 0; ch < 2; ++ch) {
        const int cb = ch * 8;
#pragma unroll
        for (int i = 0; i < 8; ++i) {
            const void* src = yok ? (const void*)(f2row + ((size_t)(cb + i) << 14))
                                  : (const void*)zrow;
            gload16(src, sF + i * 4096 + wv * 1024);
        }
        __syncthreads();
#pragma unroll
        for (int i = 0; i < 8; ++i) {
            float4 a = f1p[(size_t)(cb + i) << 14];
            const char* base = sF + i * 4096 + rloc * 2048;
#pragma unroll
            for (int pw = 0; pw < 11; ++pw) {
                int x = w + pw - 5;
                if ((unsigned)x < (unsigned)WW) {
                    float4 c = *(const float4*)(base + x * 16);
                    acc[pw] = fmaf(a.x, c.x, acc[pw]);
                    acc[pw] = fmaf(a.y, c.y, acc[pw]);
                    acc[pw] = fmaf(a.z, c.z, acc[pw]);
                    acc[pw] = fmaf(a.w, c.w, acc[pw]);
                }
            }
        }
        __syncthreads();
    }

    float* Dq = D + ((((size_t)b * 121) + q * 11) << 14) + hw;
#pragma unroll
    for (int pw = 0; pw < 11; ++pw) Dq[(size_t)pw << 14] = acc[pw];
}

// ---------------- stage1 body: box-sum + top-4 within one ph chunk ----------------
__device__ void topk_s1_body(int bid, const float* __restrict__ D,
                             float4* __restrict__ Pv, int4* __restrict__ Pp)
{
    const int pix = (bid & 127) * 256 + threadIdx.x;
    const int q = bid >> 7;
    const int b = pix >> 14, hw = pix & (HWSZ - 1), h = hw >> 7, w = hw & 127;
    const int lane = threadIdx.x & 63;
    const float* Db = D + (((size_t)b * 121) << 14);

    float bv[4] = {-1e30f, -1e30f, -1e30f, -1e30f};
    int   bi[4] = {1 << 20, 1 << 20, 1 << 20, 1 << 20};

    for (int pw = 0; pw < 11; ++pw) {
        const int p = q * 11 + pw;
        const float* Dp = Db + ((size_t)p << 14);
        float v = 0.f, vx = 0.f;
#pragma unroll
        for (int dy = -1; dy <= 1; ++dy) {
            int y = h + dy;
            if ((unsigned)y < HH) {
                v += Dp[(y << 7) + w];
                if (lane == 0) { if (w > 0) vx += Dp[(y << 7) + w - 1]; }
                else if (lane == 63) { if (w < 127) vx += Dp[(y << 7) + w + 1]; }
            }
        }
        float vl = __shfl_up(v, 1);
        float vr = __shfl_down(v, 1);
        if (lane == 0)  vl = (w > 0)   ? vx : 0.f;
        if (lane == 63) vr = (w < 127) ? vx : 0.f;
        float s = vl + v + vr;
        if (s > bv[3]) {     // ascending p within thread -> stable
            if (s > bv[0]) { bv[3]=bv[2];bi[3]=bi[2]; bv[2]=bv[1];bi[2]=bi[1]; bv[1]=bv[0];bi[1]=bi[0]; bv[0]=s; bi[0]=p; }
            else if (s > bv[1]) { bv[3]=bv[2];bi[3]=bi[2]; bv[2]=bv[1];bi[2]=bi[1]; bv[1]=s; bi[1]=p; }
            else if (s > bv[2]) { bv[3]=bv[2];bi[3]=bi[2]; bv[2]=s; bi[2]=p; }
            else { bv[3]=s; bi[3]=p; }
        }
    }
    Pv[(size_t)q * 32768 + pix] = make_float4(bv[0], bv[1], bv[2], bv[3]);
    Pp[(size_t)q * 32768 + pix] = make_int4(bi[0], bi[1], bi[2], bi[3]);
}

// ---------------- stage2 body: stable merge of 11 partial top-4 lists ----------------
__device__ void topk_s2_body(int bid, const float4* __restrict__ Pv,
                             const int4* __restrict__ Pp, int* __restrict__ idxout)
{
    const int pix = bid * 256 + threadIdx.x;
    float bv2[4] = {-1e30f, -1e30f, -1e30f, -1e30f};
    int   bi2[4] = {1 << 20, 1 << 20, 1 << 20, 1 << 20};
    for (int qq = 0; qq < 11; ++qq) {
        float4 v4 = Pv[(size_t)qq * 32768 + pix];
        int4   p4 = Pp[(size_t)qq * 32768 + pix];
        float vv[4] = {v4.x, v4.y, v4.z, v4.w};
        int   pp4[4] = {p4.x, p4.y, p4.z, p4.w};
#pragma unroll
        for (int r = 0; r < 4; ++r) {
            float v = vv[r]; int pp = pp4[r];
            bool g3 = (v > bv2[3]) || (v == bv2[3] && pp < bi2[3]);
            if (g3) {
                bool g0 = (v > bv2[0]) || (v == bv2[0] && pp < bi2[0]);
                bool g1 = (v > bv2[1]) || (v == bv2[1] && pp < bi2[1]);
                bool g2 = (v > bv2[2]) || (v == bv2[2] && pp < bi2[2]);
                if (g0) { bv2[3]=bv2[2];bi2[3]=bi2[2]; bv2[2]=bv2[1];bi2[2]=bi2[1]; bv2[1]=bv2[0];bi2[1]=bi2[0]; bv2[0]=v; bi2[0]=pp; }
                else if (g1) { bv2[3]=bv2[2];bi2[3]=bi2[2]; bv2[2]=bv2[1];bi2[2]=bi2[1]; bv2[1]=v; bi2[1]=pp; }
                else if (g2) { bv2[3]=bv2[2];bi2[3]=bi2[2]; bv2[2]=v; bi2[2]=pp; }
                else { bv2[3]=v; bi2[3]=pp; }
            }
        }
    }
    int p0 = (bi2[0] / 11) | ((bi2[0] % 11) << 16);
    int p1 = (bi2[1] / 11) | ((bi2[1] % 11) << 16);
    int p2 = (bi2[2] / 11) | ((bi2[2] % 11) << 16);
    int p3 = (bi2[3] / 11) | ((bi2[3] % 11) << 16);
    ((int4*)idxout)[pix] = make_int4(p0, p1, p2, p3);
}

// ---------------- implicit-GEMM conv body (MFMA), 2-phase pipelined, LDS from pool ----------------
template<int CINPT, int OUTFMT, int BM, int BN, int WN>
__device__ void mmconv_body(int by,
    const char* __restrict__ Wb, int src_off, int rowbytes, int zoff,
    const ushort* __restrict__ WT, int Ktot,
    const float* __restrict__ bias,
    void* __restrict__ outp, int ostride, int nvalid,
    char* __restrict__ sAbuf, char* __restrict__ sBbuf)
{
    constexpr int WM = 4 / WN;
    constexpr int FM = BM / (WM * 16);
    constexpr int FN = BN / (WN * 16);
    constexpr int NA = BM / 32;
    constexpr int NB = BN / 32;
    constexpr int ASZ = BM * 128;
    constexpr int BSZ = BN * 128;
    const int n0 = 0;
    const int m0 = by * BM;
    const int tid = threadIdx.x;
    const int lane = tid & 63, wv = tid >> 6;
    const int lr = lane >> 4, lc = lane & 15;
    const int wr = wv / WN, wc = wv % WN;

    int hA[NA], wA[NA], aBase[NA], swzA[NA];
#pragma unroll
    for (int i = 0; i < NA; ++i) {
        int r  = (i * 4 + wv) * 8 + (lane >> 3);
        int pm = m0 + r;
        int hw = pm & (HWSZ - 1);
        hA[i] = hw >> 7; wA[i] = hw & 127;
        aBase[i] = src_off + (pm >> 14) * (HWSZ * rowbytes);
        swzA[i]  = ((lane & 7) ^ (r & 7)) << 4;
    }
    int boff[NB];
#pragma unroll
    for (int i = 0; i < NB; ++i) {
        int rb = (i * 4 + wv) * 8 + (lane >> 3);
        boff[i] = (n0 + rb) * Ktot * 2 + (((lane & 7) ^ (rb & 7)) << 4);
    }

    f32x4 acc[FM][FN] = {};
    const int NST = Ktot / 64;

#define CSTAGE(S, B)                                                             \
    {                                                                            \
        int k0 = (S) * 64;                                                       \
        int tap = k0 / CINPT;                                                    \
        int c0b = (k0 % CINPT) * 2;                                              \
        int du = tap / 3 - 1, dv = tap % 3 - 1;                                  \
        _Pragma("unroll")                                                        \
        for (int i = 0; i < NA; ++i) {                                           \
            int y = hA[i] + du, x = wA[i] + dv;                                  \
            bool ok = ((unsigned)y < (unsigned)HH) && ((unsigned)x < (unsigned)WW); \
            int off = ok ? (aBase[i] + ((y << 7) + x) * rowbytes + c0b + swzA[i]) : zoff; \
            gload16(Wb + (unsigned)off, sAbuf + (B) * ASZ + (i * 4 + wv) * 1024); \
        }                                                                        \
        _Pragma("unroll")                                                        \
        for (int i = 0; i < NB; ++i)                                             \
            gload16((const char*)WT + (unsigned)(boff[i] + (S) * 128),           \
                    sBbuf + (B) * BSZ + (i * 4 + wv) * 1024);                    \
    }

    CSTAGE(0, 0)
    __syncthreads();
#pragma unroll 1
    for (int s = 0; s < NST; ++s) {
        if (s + 1 < NST) { CSTAGE(s + 1, (s + 1) & 1) }
        const char* cA = sAbuf + (s & 1) * ASZ;
        const char* cB = sBbuf + (s & 1) * BSZ;
#pragma unroll
        for (int ks = 0; ks < 2; ++ks) {
            short8 af[FM]; short8 bfr[FN];
            const int u = ks * 4 + lr;
#pragma unroll
            for (int f = 0; f < FM; ++f) {
                int rr = wr * (FM * 16) + f * 16 + lc;
                af[f] = *(const short8*)&cA[rr * 128 + ((u ^ (rr & 7)) << 4)];
            }
#pragma unroll
            for (int g = 0; g < FN; ++g) {
                int nn = wc * (FN * 16) + g * 16 + lc;
                bfr[g] = *(const short8*)&cB[nn * 128 + ((u ^ (nn & 7)) << 4)];
            }
#pragma unroll
            for (int f = 0; f < FM; ++f)
#pragma unroll
                for (int g = 0; g < FN; ++g)
                    acc[f][g] = __builtin_amdgcn_mfma_f32_16x16x32_bf16(af[f], bfr[g], acc[f][g], 0, 0, 0);
        }
        __syncthreads();
    }
#undef CSTAGE

#pragma unroll
    for (int f = 0; f < FM; ++f)
#pragma unroll
        for (int g = 0; g < FN; ++g) {
            const int col = n0 + wc * (FN * 16) + g * 16 + lc;
            float bv = (bias != nullptr && col < nvalid) ? bias[col] : 0.f;
            if (OUTFMT == 2) {
                const int mb = m0 + wr * (FM * 16) + f * 16 + lr * 4;
                const int bb = mb >> 14, hww = mb & (HWSZ - 1);
                float4 o4 = {acc[f][g][0] + bv, acc[f][g][1] + bv,
                             acc[f][g][2] + bv, acc[f][g][3] + bv};
                *(float4*)((float*)outp + (((size_t)(bb * 64 + col)) << 14) + hww) = o4;
            } else {
#pragma unroll
                for (int reg = 0; reg < 4; ++reg) {
                    const int m = m0 + wr * (FM * 16) + f * 16 + lr * 4 + reg;
                    float v = acc[f][g][reg] + bv;
                    if (OUTFMT == 0)
                        ((ushort*)outp)[(size_t)m * ostride + col] = f2bf(v);
                    else if (col < nvalid)
                        ((float*)outp)[(size_t)m * ostride + col] = v;
                }
            }
        }
}

// ---------------- fused dispatch kernels ----------------
__global__ __launch_bounds__(256) void k0_prep_l2t2(
    const float* __restrict__ ref, const float* __restrict__ nbr,
    const float* __restrict__ c1w, const float* __restrict__ c2w,
    const float* __restrict__ mw,  const float* __restrict__ aw,
    const float* __restrict__ nnw, char* __restrict__ W)
{
    const int bid = blockIdx.x;
    if (bid < 512) {
        l2t2_body(bid, ref, (float4*)(W + OFF_F1T),
                  (ushort*)(W + OFF_CATT) + 64, (ushort*)(W + OFF_CAT2T) + 64);
    } else if (bid < 1024) {
        l2t2_body(bid - 512, nbr, (float4*)(W + OFF_F2T),
                  (ushort*)(W + OFF_CATT), (ushort*)nullptr);
    } else {
        prep_body(bid - 1024, c1w, c2w, mw, aw, nnw, W);
    }
}

__global__ __launch_bounds__(256) void k1_conv1_dot(
    char* __restrict__ W, const float* __restrict__ c1b)
{
    __shared__ __align__(16) char pool[32768];
    const int bid = blockIdx.x;
    if (bid < 1408) {   // dot first: it's the critical path
        dot_body(bid, (const float4*)(W + OFF_F1T),
                 (const float4*)(W + OFF_F2T), (float*)(W + OFF_D),
                 W + OFF_ZROW, pool);
    } else {
        mmconv_body<128, 0, 32, 64, 4>(bid - 1408, W, OFF_CATT, 256, OFF_ZROW,
            (ushort*)(W + OFF_WT1), 1152, c1b, W + OFF_WF1, 64, 64,
            pool, pool + 8192);
    }
}

__global__ __launch_bounds__(256) void k2_conv2_s1(
    char* __restrict__ W, const float* __restrict__ c2b)
{
    __shared__ __align__(16) char pool[24576];
    const int bid = blockIdx.x;
    if (bid < 1408) {
        topk_s1_body(bid, (const float*)(W + OFF_D),
                     (float4*)(W + OFF_PV), (int4*)(W + OFF_PP));
    } else {
        mmconv_body<64, 0, 32, 64, 4>(bid - 1408, W, OFF_WF1, 128, OFF_ZROW,
            (ushort*)(W + OFF_WT2), 576, c2b, W + OFF_WF2, 64, 64,
            pool, pool + 8192);
    }
}

__global__ __launch_bounds__(256) void k3_convM_s2(
    char* __restrict__ W, const float* __restrict__ mb)
{
    __shared__ __align__(16) char pool[32768];
    const int bid = blockIdx.x;
    if (bid < 1024) {
        mmconv_body<64, 1, 32, 96, 2>(bid, W, OFF_WF2, 128, OFF_ZROW,
            (ushort*)(W + OFF_WTM), 576, mb, (float*)(W + OFF_MASK), 72, 72,
            pool, pool + 8192);
    } else {
        topk_s2_body(bid - 1024, (const float4*)(W + OFF_PV),
                     (const int4*)(W + OFF_PP), (int*)(W + OFF_IDX));
    }
}

__global__ __launch_bounds__(256) void convA_kernel(
    char* __restrict__ W, const float* __restrict__ ab, float* __restrict__ out)
{
    __shared__ __align__(16) char pool[24576];
    mmconv_body<128, 2, 32, 64, 4>(blockIdx.x, W, OFF_CAT2T, 256, OFF_ZROW,
        (ushort*)(W + OFF_WTA), 1152, ab, out, 0, 64, pool, pool + 8192);
}

// ---------------- stage-4: pipelined gathered patch-GEMM, 1-e B slots (3 blocks/CU) ----------------
// LDS = 36,864 A + 2x8,192 B = 53,248 -> 3 blocks/CU. Global e-counter ge=j*9+e; B(ge) in
// slot ge&1; B(ge+1) issued at e; A(j+1) issued at e==1 (sA dead after af->regs).
__global__ __launch_bounds__(256, 3) void patch_kernel(
    const char* __restrict__ Wb, int cat_off, int idx_off, int zoff, int wb_off,
    const float* __restrict__ maskcl, const float* __restrict__ nnb,
    ushort* __restrict__ aggout)
{
    const int m0 = blockIdx.x * 32;
    const int tid = threadIdx.x;
    const int lane = tid & 63, wv = tid >> 6;
    const int lr = lane >> 4, lc = lane & 15;
    const int wr = wv >> 1, wc = wv & 1;

    __shared__ __align__(16) char sP[36864 + 2 * 8192];   // 53248 B

    const int r    = tid >> 3;
    const int pm_s = m0 + r;
    const int hw_s = pm_s & (HWSZ - 1);
    const int hS = hw_s >> 7, wS = hw_s & 127;
    const int aBase = cat_off + (pm_s >> 14) * (HWSZ * 256);
    const int swzA  = ((tid & 7) ^ (r & 7)) << 4;
    int bsrc[2];
#pragma unroll
    for (int i = 0; i < 2; ++i) {
        int rl = i * 32 + r;
        bsrc[i] = wb_off + rl * 128 + (((tid & 7) ^ (rl & 7)) << 4);
    }
    const int4 pk4 = ((const int4*)(Wb + idx_off))[pm_s];

    f32x4 acc[9][2] = {};

#define ISSUE_A(PK)                                                              \
    {                                                                            \
        const int hp = hS + ((PK) & 0xffff) - 6;                                 \
        const int wp = wS + ((PK) >> 16) - 6;                                    \
        _Pragma("unroll")                                                        \
        for (int uv = 0; uv < 9; ++uv) {                                         \
            int y = hp + uv / 3, x = wp + uv % 3;                                \
            bool ok = ((unsigned)y < (unsigned)HH) && ((unsigned)x < (unsigned)WW); \
            int off = ok ? (aBase + ((y << 7) + x) * 256 + swzA) : zoff;         \
            gload16(Wb + (unsigned)off, &sP[uv * 4096 + wv * 1024]);             \
        }                                                                        \
    }
#define ISSUE_B1(GE)                                                             \
    {                                                                            \
        const int jj = (GE) / 9, ne = (GE) % 9;                                  \
        _Pragma("unroll")                                                        \
        for (int i = 0; i < 2; ++i)                                              \
            gload16(Wb + (unsigned)(bsrc[i] + jj * 73728 + ne * 8192),           \
                    &sP[36864 + ((GE) & 1) * 8192 + i * 4096 + wv * 1024]);      \
    }

    // prologue: A(0) + B(ge=0) -> slot0
    ISSUE_A(pk4.x)
    ISSUE_B1(0)
    __syncthreads();

#pragma unroll 1
    for (int j = 0; j < 4; ++j) {
        short8 af[9][2];
#pragma unroll
        for (int uv = 0; uv < 9; ++uv)
#pragma unroll
            for (int ks = 0; ks < 2; ++ks) {
                const int rr = wr * 16 + lc;
                af[uv][ks] = *(const short8*)&sP[uv * 4096 + rr * 128 +
                                                (((ks * 4 + lr) ^ (rr & 7)) << 4)];
            }

#pragma unroll
        for (int e = 0; e < 9; ++e) {
            const int ge = j * 9 + e;
            if (e == 1 && j < 3) {   // sA dead (af in regs, e0 barrier passed): prefetch A(j+1)
                const int pkn = (j == 0) ? pk4.y : (j == 1) ? pk4.z : pk4.w;
                ISSUE_A(pkn)
            }
            if (ge + 1 < 36) { ISSUE_B1(ge + 1) }

            const char* bt = &sP[36864 + (ge & 1) * 8192];
            short8 bfr[2][2];
#pragma unroll
            for (int gg = 0; gg < 2; ++gg) {
                const int rloc = wc * 32 + gg * 16 + lc;
#pragma unroll
                for (int ks = 0; ks < 2; ++ks)
                    bfr[gg][ks] = *(const short8*)&bt[rloc * 128 +
                                                      (((ks * 4 + lr) ^ (rloc & 7)) << 4)];
            }
            const int ky = e / 3, kx = e % 3;
#pragma unroll
            for (int uv = 0; uv < 9; ++uv) {
                const int uu = uv / 3, vv = uv % 3;
                const int ty = uu - ky + 1, tx = vv - kx + 1;
                if (ty < 0 || ty > 2 || tx < 0 || tx > 2) continue;
                const int t = ty * 3 + tx;
#pragma unroll
                for (int gg = 0; gg < 2; ++gg) {
                    acc[t][gg] = __builtin_amdgcn_mfma_f32_16x16x32_bf16(af[uv][0], bfr[gg][0], acc[t][gg], 0, 0, 0);
                    acc[t][gg] = __builtin_amdgcn_mfma_f32_16x16x32_bf16(af[uv][1], bfr[gg][1], acc[t][gg], 0, 0, 0);
                }
            }
            __syncthreads();
        }
    }
#undef ISSUE_A
#undef ISSUE_B1

    // fused combine: s(m,o) = LeakyReLU( sum_t (acc_t + nn_b[o]) * mask[m][g(o)*9+t] )
#pragma unroll
    for (int gg = 0; gg < 2; ++gg) {
        const int col_o = wc * 32 + gg * 16 + lc;
        const float bo = nnb[col_o];
        const int og = col_o >> 3;
#pragma unroll
        for (int reg = 0; reg < 4; ++reg) {
            const int m = m0 + wr * 16 + lr * 4 + reg;
            const float* mp = maskcl + (size_t)m * 72 + og * 9;
            float s = 0.f;
#pragma unroll
            for (int t = 0; t < 9; ++t) s += (acc[t][gg][reg] + bo) * mp[t];
            s = (s >= 0.f) ? s : 0.1f * s;
            aggout[(size_t)m * 128 + col_o] = f2bf(s);
        }
    }
}

extern "C" void kernel_launch(void* const* d_in, const int* in_sizes, int n_in,
                              void* d_out, int out_size, void* d_ws, size_t ws_size,
                              hipStream_t stream)
{
    const float* nbr = (const float*)d_in[0];
    const float* ref = (const float*)d_in[1];
    const float* c1w = (const float*)d_in[2];
    const float* c1b = (const float*)d_in[3];
    const float* c2w = (const float*)d_in[4];
    const float* c2b = (const float*)d_in[5];
    const float* mw  = (const float*)d_in[6];
    const float* mb  = (const float*)d_in[7];
    const float* nnw = (const float*)d_in[8];
    const float* nnb = (const float*)d_in[9];
    const float* aw  = (const float*)d_in[10];
    const float* ab  = (const float*)d_in[11];
    float* out = (float*)d_out;

    char* W = (char*)d_ws;
    dim3 blk(256);

    // K0: prep ∥ l2t2(ref) ∥ l2t2(nbr)
    k0_prep_l2t2<<<2537, blk, 0, stream>>>(ref, nbr, c1w, c2w, mw, aw, nnw, W);

    // K1: dot (LDS-staged f2 rows) ∥ conv1
    k1_conv1_dot<<<2432, blk, 0, stream>>>(W, c1b);

    // K2: topk_s1 ∥ conv2
    k2_conv2_s1<<<2432, blk, 0, stream>>>(W, c2b);

    // K3: convM ∥ topk_s2
    k3_convM_s2<<<1152, blk, 0, stream>>>(W, mb);

    // stage-4 gathered patch-GEMM + fused combine -> agg half of cat2T
    patch_kernel<<<1024, blk, 0, stream>>>(W, OFF_CATT, OFF_IDX, OFF_ZROW, OFF_WB,
                                           (const float*)(W + OFF_MASK), nnb,
                                           (ushort*)(W + OFF_CAT2T));

    // final conv on concat(agg, ref) -> NCHW fp32 d_out (float4 stores)
    convA_kernel<<<1024, blk, 0, stream>>>(W, ab, out);
}

// Round 20
// 145.913 us; speedup vs baseline: 1.0537x; 1.0537x over previous
//
#include <hip/hip_runtime.h>
#include <hip/hip_bf16.h>
#include <math.h>

#define HH 128
#define WW 128
#define HWSZ 16384

typedef __attribute__((ext_vector_type(8))) short short8;
typedef __attribute__((ext_vector_type(4))) float f32x4;

// ---- workspace layout (bytes) ----
constexpr int OFF_CATT  = 0;           // 8,388,608  [pix][128] bf16: nbr@0, ref@64
constexpr int OFF_CAT2T = 8388608;     // 8,388,608  [pix][128] bf16: agg@0, ref@64
constexpr int OFF_WF1   = 16777216;    // 4,194,304  [pix][64] bf16
constexpr int OFF_WF2   = 20971520;    // 4,194,304
constexpr int OFF_MASK  = 25165824;    // 9,437,184  [pix][72] fp32
constexpr int OFF_IDX   = 34603008;    //   524,288  [pix] int4 packed ph|pw<<16
constexpr int OFF_WT1   = 35127296;    //   147,456  [64][1152] bf16
constexpr int OFF_WT2   = 35274752;    //    73,728  [64][576]
constexpr int OFF_WTM   = 35348480;    //   110,592  [96][576] (rows>=72 zero)
constexpr int OFF_WTA   = 35495936;    //   147,456  [64][1152]
constexpr int OFF_ZROW  = 35643392;    //       256  zeros (OOB gather target)
constexpr int OFF_WB    = 35644416;    //   294,912  [4][576][64] bf16 plain
constexpr int OFF_F1T   = 38797312;    // 8,388,608  fp32 c4-chunked [b][16][hw][4]
constexpr int OFF_F2T   = 47185920;    // 8,388,608
constexpr int OFF_D     = 55574528;    // 15,859,712 (dead after topk_s1)
constexpr int OFF_PV    = 71434240;    // 5,767,168  float4 [11][32768]
constexpr int OFF_PP    = 77201408;    // 5,767,168  int4   [11][32768]

__device__ inline ushort f2bf(float f) {
    __hip_bfloat16 h = __float2bfloat16(f);
    return *reinterpret_cast<ushort*>(&h);
}
__device__ inline float bf2f(ushort u) {
    return __uint_as_float(((unsigned)u) << 16);
}

// async global->LDS, 16B per lane; LDS dest = wave-uniform base + lane*16
__device__ inline void gload16(const void* g, void* l) {
    __builtin_amdgcn_global_load_lds(
        (const __attribute__((address_space(1))) unsigned int*)g,
        (__attribute__((address_space(3))) unsigned int*)l, 16, 0, 0);
}

// ---------------- l2norm+transpose body ----------------
__device__ void l2t2_body(int bid, const float* __restrict__ in,
                          float4* __restrict__ normT4,
                          ushort* __restrict__ d1, ushort* __restrict__ d2)
{
    const int pix0 = bid * 64;
    const int b = pix0 >> 14;
    const int hw0 = pix0 & (HWSZ - 1);
    __shared__ float s[64][65];
    __shared__ float sinv[64];
    const int tid = threadIdx.x;
    {
        const int p = tid & 63, c4 = tid >> 6;
#pragma unroll
        for (int r = 0; r < 16; ++r) {
            int c = r * 4 + c4;
            s[c][p] = in[(((size_t)b * 64 + c) << 14) + hw0 + p];
        }
    }
    __syncthreads();
    if (tid < 64) {
        float sum = 0.f;
#pragma unroll
        for (int c = 0; c < 64; ++c) { float v = s[c][tid]; sum = fmaf(v, v, sum); }
        sinv[tid] = 1.f / fmaxf(sqrtf(sum), 1e-12f);
    }
    __syncthreads();
    {
        const int pp = tid & 63, cg = tid >> 6;
        const float inv = sinv[pp];
#pragma unroll
        for (int r = 0; r < 4; ++r) {
            int c4 = cg * 4 + r;
            float4 v = make_float4(s[c4 * 4 + 0][pp] * inv, s[c4 * 4 + 1][pp] * inv,
                                   s[c4 * 4 + 2][pp] * inv, s[c4 * 4 + 3][pp] * inv);
            normT4[(((size_t)b * 16 + c4) << 14) + hw0 + pp] = v;
        }
    }
    {
        const int c = tid & 63, p4 = tid >> 6;
#pragma unroll
        for (int r = 0; r < 16; ++r) {
            int pp = r * 4 + p4;
            ushort bv = f2bf(s[c][pp]);
            d1[(size_t)(pix0 + pp) * 128 + c] = bv;
            if (d2) d2[(size_t)(pix0 + pp) * 128 + c] = bv;
        }
    }
}

// ---------------- fused weight prep body ----------------
__device__ inline ushort wt_elem(const float* __restrict__ w, int Cin, int Cout, int idx) {
    int kc = 9 * Cin;
    int o = idx / kc, rem = idx % kc;
    int tap = rem / Cin, c = rem % Cin;
    float val = (o < Cout) ? w[((size_t)o * Cin + c) * 9 + tap] : 0.f;
    return f2bf(val);
}

__device__ void prep_body(int bid,
                          const float* __restrict__ c1w, const float* __restrict__ c2w,
                          const float* __restrict__ mw,  const float* __restrict__ aw,
                          const float* __restrict__ nnw, char* __restrict__ W)
{
    int gid = bid * 256 + threadIdx.x;   // 387200 total
    if (gid < 73728) {
        ((ushort*)(W + OFF_WT1))[gid] = wt_elem(c1w, 128, 64, gid);
    } else if (gid < 110592) {
        int i = gid - 73728;
        ((ushort*)(W + OFF_WT2))[i] = wt_elem(c2w, 64, 64, i);
    } else if (gid < 165888) {
        int i = gid - 110592;
        ((ushort*)(W + OFF_WTM))[i] = wt_elem(mw, 64, 72, i);
    } else if (gid < 239616) {
        int i = gid - 165888;
        ((ushort*)(W + OFF_WTA))[i] = wt_elem(aw, 128, 64, i);
    } else if (gid < 387072) {
        int idx = gid - 239616;
        int j = idx / 36864, rem = idx % 36864;
        int rb = rem >> 6, c = rem & 63;
        int e = rb >> 6, o = rb & 63;
        int ky = e / 3, kx = e % 3;
        ((ushort*)(W + OFF_WB))[idx] =
            f2bf(nnw[(((size_t)o * 256 + j * 64 + c) * 3 + ky) * 3 + kx]);
    } else if (gid < 387200) {
        ((ushort*)(W + OFF_ZROW))[gid - 387072] = 0;
    }
}

// ---------------- dots via LDS-staged f2 rows (2 rows, 8-c4 chunks) ----------------
__device__ void dot_body(int bid, const float4* __restrict__ f1t4,
                         const float4* __restrict__ f2t4, float* __restrict__ D,
                         const char* __restrict__ zrow, char* __restrict__ sF)
{
    const int q  = bid / 128;
    const int rr = bid % 128;
    const int b  = rr >> 6;
    const int hp = rr & 63;
    const int tid = threadIdx.x;
    const int w = tid & 127, rloc = tid >> 7;
    const int wv = tid >> 6;
    const int h = hp * 2 + rloc;
    const int hw = (h << 7) + w;
    const int y = h + q - 5;
    const bool yok = (unsigned)y < (unsigned)HH;

    float acc[11] = {};
    const float4* f1p = f1t4 + (((size_t)b * 16) << 14) + hw;
    const float4* f2row = f2t4 + (((size_t)b * 16) << 14) + (y << 7) + w;

#pragma unroll 1
    for (int ch = 0; ch < 2; ++ch) {
        const int cb = ch * 8;
#pragma unroll
        for (int i = 0; i < 8; ++i) {
            const void* src = yok ? (const void*)(f2row + ((size_t)(cb + i) << 14))
                                  : (const void*)zrow;
            gload16(src, sF + i * 4096 + wv * 1024);
        }
        __syncthreads();
#pragma unroll
        for (int i = 0; i < 8; ++i) {
            float4 a = f1p[(size_t)(cb + i) << 14];
            const char* base = sF + i * 4096 + rloc * 2048;
#pragma unroll
            for (int pw = 0; pw < 11; ++pw) {
                int x = w + pw - 5;
                if ((unsigned)x < (unsigned)WW) {
                    float4 c = *(const float4*)(base + x * 16);
                    acc[pw] = fmaf(a.x, c.x, acc[pw]);
                    acc[pw] = fmaf(a.y, c.y, acc[pw]);
                    acc[pw] = fmaf(a.z, c.z, acc[pw]);
                    acc[pw] = fmaf(a.w, c.w, acc[pw]);
                }
            }
        }
        __syncthreads();
    }

    float* Dq = D + ((((size_t)b * 121) + q * 11) << 14) + hw;
#pragma unroll
    for (int pw = 0; pw < 11; ++pw) Dq[(size_t)pw << 14] = acc[pw];
}

// ---------------- stage1 body: box-sum + top-4 within one ph chunk ----------------
__device__ void topk_s1_body(int bid, const float* __restrict__ D,
                             float4* __restrict__ Pv, int4* __restrict__ Pp)
{
    const int pix = (bid & 127) * 256 + threadIdx.x;
    const int q = bid >> 7;
    const int b = pix >> 14, hw = pix & (HWSZ - 1), h = hw >> 7, w = hw & 127;
    const int lane = threadIdx.x & 63;
    const float* Db = D + (((size_t)b * 121) << 14);

    float bv[4] = {-1e30f, -1e30f, -1e30f, -1e30f};
    int   bi[4] = {1 << 20, 1 << 20, 1 << 20, 1 << 20};

    for (int pw = 0; pw < 11; ++pw) {
        const int p = q * 11 + pw;
        const float* Dp = Db + ((size_t)p << 14);
        float v = 0.f, vx = 0.f;
#pragma unroll
        for (int dy = -1; dy <= 1; ++dy) {
            int y = h + dy;
            if ((unsigned)y < HH) {
                v += Dp[(y << 7) + w];
                if (lane == 0) { if (w > 0) vx += Dp[(y << 7) + w - 1]; }
                else if (lane == 63) { if (w < 127) vx += Dp[(y << 7) + w + 1]; }
            }
        }
        float vl = __shfl_up(v, 1);
        float vr = __shfl_down(v, 1);
        if (lane == 0)  vl = (w > 0)   ? vx : 0.f;
        if (lane == 63) vr = (w < 127) ? vx : 0.f;
        float s = vl + v + vr;
        if (s > bv[3]) {     // ascending p within thread -> stable
            if (s > bv[0]) { bv[3]=bv[2];bi[3]=bi[2]; bv[2]=bv[1];bi[2]=bi[1]; bv[1]=bv[0];bi[1]=bi[0]; bv[0]=s; bi[0]=p; }
            else if (s > bv[1]) { bv[3]=bv[2];bi[3]=bi[2]; bv[2]=bv[1];bi[2]=bi[1]; bv[1]=s; bi[1]=p; }
            else if (s > bv[2]) { bv[3]=bv[2];bi[3]=bi[2]; bv[2]=s; bi[2]=p; }
            else { bv[3]=s; bi[3]=p; }
        }
    }
    Pv[(size_t)q * 32768 + pix] = make_float4(bv[0], bv[1], bv[2], bv[3]);
    Pp[(size_t)q * 32768 + pix] = make_int4(bi[0], bi[1], bi[2], bi[3]);
}

// ---------------- stage2 body: stable merge of 11 partial top-4 lists ----------------
__device__ void topk_s2_body(int bid, const float4* __restrict__ Pv,
                             const int4* __restrict__ Pp, int* __restrict__ idxout)
{
    const int pix = bid * 256 + threadIdx.x;
    float bv2[4] = {-1e30f, -1e30f, -1e30f, -1e30f};
    int   bi2[4] = {1 << 20, 1 << 20, 1 << 20, 1 << 20};
    for (int qq = 0; qq < 11; ++qq) {
        float4 v4 = Pv[(size_t)qq * 32768 + pix];
        int4   p4 = Pp[(size_t)qq * 32768 + pix];
        float vv[4] = {v4.x, v4.y, v4.z, v4.w};
        int   pp4[4] = {p4.x, p4.y, p4.z, p4.w};
#pragma unroll
        for (int r = 0; r < 4; ++r) {
            float v = vv[r]; int pp = pp4[r];
            bool g3 = (v > bv2[3]) || (v == bv2[3] && pp < bi2[3]);
            if (g3) {
                bool g0 = (v > bv2[0]) || (v == bv2[0] && pp < bi2[0]);
                bool g1 = (v > bv2[1]) || (v == bv2[1] && pp < bi2[1]);
                bool g2 = (v > bv2[2]) || (v == bv2[2] && pp < bi2[2]);
                if (g0) { bv2[3]=bv2[2];bi2[3]=bi2[2]; bv2[2]=bv2[1];bi2[2]=bi2[1]; bv2[1]=bv2[0];bi2[1]=bi2[0]; bv2[0]=v; bi2[0]=pp; }
                else if (g1) { bv2[3]=bv2[2];bi2[3]=bi2[2]; bv2[2]=bv2[1];bi2[2]=bi2[1]; bv2[1]=v; bi2[1]=pp; }
                else if (g2) { bv2[3]=bv2[2];bi2[3]=bi2[2]; bv2[2]=v; bi2[2]=pp; }
                else { bv2[3]=v; bi2[3]=pp; }
            }
        }
    }
    int p0 = (bi2[0] / 11) | ((bi2[0] % 11) << 16);
    int p1 = (bi2[1] / 11) | ((bi2[1] % 11) << 16);
    int p2 = (bi2[2] / 11) | ((bi2[2] % 11) << 16);
    int p3 = (bi2[3] / 11) | ((bi2[3] % 11) << 16);
    ((int4*)idxout)[pix] = make_int4(p0, p1, p2, p3);
}

// ---------------- implicit-GEMM conv body (MFMA), 2-phase pipelined, LDS from pool ----------------
template<int CINPT, int OUTFMT, int BM, int BN, int WN>
__device__ void mmconv_body(int by,
    const char* __restrict__ Wb, int src_off, int rowbytes, int zoff,
    const ushort* __restrict__ WT, int Ktot,
    const float* __restrict__ bias,
    void* __restrict__ outp, int ostride, int nvalid,
    char* __restrict__ sAbuf, char* __restrict__ sBbuf)
{
    constexpr int WM = 4 / WN;
    constexpr int FM = BM / (WM * 16);
    constexpr int FN = BN / (WN * 16);
    constexpr int NA = BM / 32;
    constexpr int NB = BN / 32;
    constexpr int ASZ = BM * 128;
    constexpr int BSZ = BN * 128;
    const int n0 = 0;
    const int m0 = by * BM;
    const int tid = threadIdx.x;
    const int lane = tid & 63, wv = tid >> 6;
    const int lr = lane >> 4, lc = lane & 15;
    const int wr = wv / WN, wc = wv % WN;

    int hA[NA], wA[NA], aBase[NA], swzA[NA];
#pragma unroll
    for (int i = 0; i < NA; ++i) {
        int r  = (i * 4 + wv) * 8 + (lane >> 3);
        int pm = m0 + r;
        int hw = pm & (HWSZ - 1);
        hA[i] = hw >> 7; wA[i] = hw & 127;
        aBase[i] = src_off + (pm >> 14) * (HWSZ * rowbytes);
        swzA[i]  = ((lane & 7) ^ (r & 7)) << 4;
    }
    int boff[NB];
#pragma unroll
    for (int i = 0; i < NB; ++i) {
        int rb = (i * 4 + wv) * 8 + (lane >> 3);
        boff[i] = (n0 + rb) * Ktot * 2 + (((lane & 7) ^ (rb & 7)) << 4);
    }

    f32x4 acc[FM][FN] = {};
    const int NST = Ktot / 64;

#define CSTAGE(S, B)                                                             \
    {                                                                            \
        int k0 = (S) * 64;                                                       \
        int tap = k0 / CINPT;                                                    \
        int c0b = (k0 % CINPT) * 2;                                              \
        int du = tap / 3 - 1, dv = tap % 3 - 1;                                  \
        _Pragma("unroll")                                                        \
        for (int i = 0; i < NA; ++i) {                                           \
            int y = hA[i] + du, x = wA[i] + dv;                                  \
            bool ok = ((unsigned)y < (unsigned)HH) && ((unsigned)x < (unsigned)WW); \
            int off = ok ? (aBase[i] + ((y << 7) + x) * rowbytes + c0b + swzA[i]) : zoff; \
            gload16(Wb + (unsigned)off, sAbuf + (B) * ASZ + (i * 4 + wv) * 1024); \
        }                                                                        \
        _Pragma("unroll")                                                        \
        for (int i = 0; i < NB; ++i)                                             \
            gload16((const char*)WT + (unsigned)(boff[i] + (S) * 128),           \
                    sBbuf + (B) * BSZ + (i * 4 + wv) * 1024);                    \
    }

    CSTAGE(0, 0)
    __syncthreads();
#pragma unroll 1
    for (int s = 0; s < NST; ++s) {
        if (s + 1 < NST) { CSTAGE(s + 1, (s + 1) & 1) }
        const char* cA = sAbuf + (s & 1) * ASZ;
        const char* cB = sBbuf + (s & 1) * BSZ;
#pragma unroll
        for (int ks = 0; ks < 2; ++ks) {
            short8 af[FM]; short8 bfr[FN];
            const int u = ks * 4 + lr;
#pragma unroll
            for (int f = 0; f < FM; ++f) {
                int rr = wr * (FM * 16) + f * 16 + lc;
                af[f] = *(const short8*)&cA[rr * 128 + ((u ^ (rr & 7)) << 4)];
            }
#pragma unroll
            for (int g = 0; g < FN; ++g) {
                int nn = wc * (FN * 16) + g * 16 + lc;
                bfr[g] = *(const short8*)&cB[nn * 128 + ((u ^ (nn & 7)) << 4)];
            }
#pragma unroll
            for (int f = 0; f < FM; ++f)
#pragma unroll
                for (int g = 0; g < FN; ++g)
                    acc[f][g] = __builtin_amdgcn_mfma_f32_16x16x32_bf16(af[f], bfr[g], acc[f][g], 0, 0, 0);
        }
        __syncthreads();
    }
#undef CSTAGE

#pragma unroll
    for (int f = 0; f < FM; ++f)
#pragma unroll
        for (int g = 0; g < FN; ++g) {
            const int col = n0 + wc * (FN * 16) + g * 16 + lc;
            float bv = (bias != nullptr && col < nvalid) ? bias[col] : 0.f;
            if (OUTFMT == 2) {
                const int mb = m0 + wr * (FM * 16) + f * 16 + lr * 4;
                const int bb = mb >> 14, hww = mb & (HWSZ - 1);
                float4 o4 = {acc[f][g][0] + bv, acc[f][g][1] + bv,
                             acc[f][g][2] + bv, acc[f][g][3] + bv};
                *(float4*)((float*)outp + (((size_t)(bb * 64 + col)) << 14) + hww) = o4;
            } else {
#pragma unroll
                for (int reg = 0; reg < 4; ++reg) {
                    const int m = m0 + wr * (FM * 16) + f * 16 + lr * 4 + reg;
                    float v = acc[f][g][reg] + bv;
                    if (OUTFMT == 0)
                        ((ushort*)outp)[(size_t)m * ostride + col] = f2bf(v);
                    else if (col < nvalid)
                        ((float*)outp)[(size_t)m * ostride + col] = v;
                }
            }
        }
}

// ---------------- fused dispatch kernels ----------------
__global__ __launch_bounds__(256) void k0_prep_l2t2(
    const float* __restrict__ ref, const float* __restrict__ nbr,
    const float* __restrict__ c1w, const float* __restrict__ c2w,
    const float* __restrict__ mw,  const float* __restrict__ aw,
    const float* __restrict__ nnw, char* __restrict__ W)
{
    const int bid = blockIdx.x;
    if (bid < 512) {
        l2t2_body(bid, ref, (float4*)(W + OFF_F1T),
                  (ushort*)(W + OFF_CATT) + 64, (ushort*)(W + OFF_CAT2T) + 64);
    } else if (bid < 1024) {
        l2t2_body(bid - 512, nbr, (float4*)(W + OFF_F2T),
                  (ushort*)(W + OFF_CATT), (ushort*)nullptr);
    } else {
        prep_body(bid - 1024, c1w, c2w, mw, aw, nnw, W);
    }
}

__global__ __launch_bounds__(256) void k1_conv1_dot(
    char* __restrict__ W, const float* __restrict__ c1b)
{
    __shared__ __align__(16) char pool[32768];
    const int bid = blockIdx.x;
    if (bid < 1408) {   // dot first: it's the critical path
        dot_body(bid, (const float4*)(W + OFF_F1T),
                 (const float4*)(W + OFF_F2T), (float*)(W + OFF_D),
                 W + OFF_ZROW, pool);
    } else {
        mmconv_body<128, 0, 32, 64, 4>(bid - 1408, W, OFF_CATT, 256, OFF_ZROW,
            (ushort*)(W + OFF_WT1), 1152, c1b, W + OFF_WF1, 64, 64,
            pool, pool + 8192);
    }
}

__global__ __launch_bounds__(256) void k2_conv2_s1(
    char* __restrict__ W, const float* __restrict__ c2b)
{
    __shared__ __align__(16) char pool[24576];
    const int bid = blockIdx.x;
    if (bid < 1408) {
        topk_s1_body(bid, (const float*)(W + OFF_D),
                     (float4*)(W + OFF_PV), (int4*)(W + OFF_PP));
    } else {
        mmconv_body<64, 0, 32, 64, 4>(bid - 1408, W, OFF_WF1, 128, OFF_ZROW,
            (ushort*)(W + OFF_WT2), 576, c2b, W + OFF_WF2, 64, 64,
            pool, pool + 8192);
    }
}

__global__ __launch_bounds__(256) void k3_convM_s2(
    char* __restrict__ W, const float* __restrict__ mb)
{
    __shared__ __align__(16) char pool[32768];
    const int bid = blockIdx.x;
    if (bid < 1024) {
        mmconv_body<64, 1, 32, 96, 2>(bid, W, OFF_WF2, 128, OFF_ZROW,
            (ushort*)(W + OFF_WTM), 576, mb, (float*)(W + OFF_MASK), 72, 72,
            pool, pool + 8192);
    } else {
        topk_s2_body(bid - 1024, (const float4*)(W + OFF_PV),
                     (const int4*)(W + OFF_PP), (int*)(W + OFF_IDX));
    }
}

__global__ __launch_bounds__(256) void convA_kernel(
    char* __restrict__ W, const float* __restrict__ ab, float* __restrict__ out)
{
    __shared__ __align__(16) char pool[24576];
    mmconv_body<128, 2, 32, 64, 4>(blockIdx.x, W, OFF_CAT2T, 256, OFF_ZROW,
        (ushort*)(W + OFF_WTA), 1152, ab, out, 0, 64, pool, pool + 8192);
}

// ---------------- stage-4: fully pipelined gathered patch-GEMM + fused combine ----------------
__global__ __launch_bounds__(256, 2) void patch_kernel(
    const char* __restrict__ Wb, int cat_off, int idx_off, int zoff, int wb_off,
    const float* __restrict__ maskcl, const float* __restrict__ nnb,
    ushort* __restrict__ aggout)
{
    const int m0 = blockIdx.x * 32;
    const int tid = threadIdx.x;
    const int lane = tid & 63, wv = tid >> 6;
    const int lr = lane >> 4, lc = lane & 15;
    const int wr = wv >> 1, wc = wv & 1;

    __shared__ __align__(16) char sP[36864 + 2 * 16384];   // 69632 B

    const int r    = tid >> 3;
    const int pm_s = m0 + r;
    const int hw_s = pm_s & (HWSZ - 1);
    const int hS = hw_s >> 7, wS = hw_s & 127;
    const int aBase = cat_off + (pm_s >> 14) * (HWSZ * 256);
    const int swzA  = ((tid & 7) ^ (r & 7)) << 4;
    int bsrc[2];
#pragma unroll
    for (int i = 0; i < 2; ++i) {
        int rl = i * 32 + r;
        bsrc[i] = wb_off + rl * 128 + (((tid & 7) ^ (rl & 7)) << 4);
    }
    const int4 pk4 = ((const int4*)(Wb + idx_off))[pm_s];

    f32x4 acc[9][2] = {};

#define ISSUE_A(PK)                                                              \
    {                                                                            \
        const int hp = hS + ((PK) & 0xffff) - 6;                                 \
        const int wp = wS + ((PK) >> 16) - 6;                                    \
        _Pragma("unroll")                                                        \
        for (int uv = 0; uv < 9; ++uv) {                                         \
            int y = hp + uv / 3, x = wp + uv % 3;                                \
            bool ok = ((unsigned)y < (unsigned)HH) && ((unsigned)x < (unsigned)WW); \
            int off = ok ? (aBase + ((y << 7) + x) * 256 + swzA) : zoff;         \
            gload16(Wb + (unsigned)off, &sP[uv * 4096 + wv * 1024]);             \
        }                                                                        \
    }
#define ISSUE_B(J, G, SLOT)                                                      \
    {                                                                            \
        _Pragma("unroll")                                                        \
        for (int eg = 0; eg < 2; ++eg) {                                         \
            const int ne = 2 * (G) + eg;                                         \
            if (ne > 8) continue;                                                \
            _Pragma("unroll")                                                    \
            for (int i = 0; i < 2; ++i)                                          \
                gload16(Wb + (unsigned)(bsrc[i] + (J) * 73728 + ne * 8192),      \
                        &sP[36864 + (SLOT) * 16384 + eg * 8192 + i * 4096 + wv * 1024]); \
        }                                                                        \
    }

    // prologue: A(0) + B(0, grp0) -> slot0
    ISSUE_A(pk4.x)
    ISSUE_B(0, 0, 0)
    __syncthreads();

#pragma unroll 1
    for (int j = 0; j < 4; ++j) {
        short8 af[9][2];
#pragma unroll
        for (int uv = 0; uv < 9; ++uv)
#pragma unroll
            for (int ks = 0; ks < 2; ++ks) {
                const int rr = wr * 16 + lc;
                af[uv][ks] = *(const short8*)&sP[uv * 4096 + rr * 128 +
                                                (((ks * 4 + lr) ^ (rr & 7)) << 4)];
            }

#pragma unroll
        for (int g = 0; g < 5; ++g) {
            const int slot = (j + g) & 1;
            if (g == 1 && j < 3) {   // sA dead (af in regs, g0 barrier passed): prefetch A(j+1)
                const int pkn = (j == 0) ? pk4.y : (j == 1) ? pk4.z : pk4.w;
                ISSUE_A(pkn)
            }
            if (g < 4) { ISSUE_B(j, g + 1, (j + g + 1) & 1) }
            else if (j < 3) { ISSUE_B(j + 1, 0, (j + 1) & 1) }

#pragma unroll
            for (int eg = 0; eg < 2; ++eg) {
                const int e = 2 * g + eg;
                if (e > 8) continue;
                const char* bt = &sP[36864 + slot * 16384 + eg * 8192];
                short8 bfr[2][2];
#pragma unroll
                for (int gg = 0; gg < 2; ++gg) {
                    const int rloc = wc * 32 + gg * 16 + lc;
#pragma unroll
                    for (int ks = 0; ks < 2; ++ks)
                        bfr[gg][ks] = *(const short8*)&bt[rloc * 128 +
                                                          (((ks * 4 + lr) ^ (rloc & 7)) << 4)];
                }
                const int ky = e / 3, kx = e % 3;
#pragma unroll
                for (int uv = 0; uv < 9; ++uv) {
                    const int uu = uv / 3, vv = uv % 3;
                    const int ty = uu - ky + 1, tx = vv - kx + 1;
                    if (ty < 0 || ty > 2 || tx < 0 || tx > 2) continue;
                    const int t = ty * 3 + tx;
#pragma unroll
                    for (int gg = 0; gg < 2; ++gg) {
                        acc[t][gg] = __builtin_amdgcn_mfma_f32_16x16x32_bf16(af[uv][0], bfr[gg][0], acc[t][gg], 0, 0, 0);
                        acc[t][gg] = __builtin_amdgcn_mfma_f32_16x16x32_bf16(af[uv][1], bfr[gg][1], acc[t][gg], 0, 0, 0);
                    }
                }
            }
            __syncthreads();
        }
    }
#undef ISSUE_A
#undef ISSUE_B

    // fused combine: s(m,o) = LeakyReLU( sum_t (acc_t + nn_b[o]) * mask[m][g(o)*9+t] )
#pragma unroll
    for (int gg = 0; gg < 2; ++gg) {
        const int col_o = wc * 32 + gg * 16 + lc;
        const float bo = nnb[col_o];
        const int og = col_o >> 3;
#pragma unroll
        for (int reg = 0; reg < 4; ++reg) {
            const int m = m0 + wr * 16 + lr * 4 + reg;
            const float* mp = maskcl + (size_t)m * 72 + og * 9;
            float s = 0.f;
#pragma unroll
            for (int t = 0; t < 9; ++t) s += (acc[t][gg][reg] + bo) * mp[t];
            s = (s >= 0.f) ? s : 0.1f * s;
            aggout[(size_t)m * 128 + col_o] = f2bf(s);
        }
    }
}

extern "C" void kernel_launch(void* const* d_in, const int* in_sizes, int n_in,
                              void* d_out, int out_size, void* d_ws, size_t ws_size,
                              hipStream_t stream)
{
    const float* nbr = (const float*)d_in[0];
    const float* ref = (const float*)d_in[1];
    const float* c1w = (const float*)d_in[2];
    const float* c1b = (const float*)d_in[3];
    const float* c2w = (const float*)d_in[4];
    const float* c2b = (const float*)d_in[5];
    const float* mw  = (const float*)d_in[6];
    const float* mb  = (const float*)d_in[7];
    const float* nnw = (const float*)d_in[8];
    const float* nnb = (const float*)d_in[9];
    const float* aw  = (const float*)d_in[10];
    const float* ab  = (const float*)d_in[11];
    float* out = (float*)d_out;

    char* W = (char*)d_ws;
    dim3 blk(256);

    // K0: prep ∥ l2t2(ref) ∥ l2t2(nbr)
    k0_prep_l2t2<<<2537, blk, 0, stream>>>(ref, nbr, c1w, c2w, mw, aw, nnw, W);

    // K1: dot (LDS-staged f2 rows) ∥ conv1
    k1_conv1_dot<<<2432, blk, 0, stream>>>(W, c1b);

    // K2: topk_s1 ∥ conv2
    k2_conv2_s1<<<2432, blk, 0, stream>>>(W, c2b);

    // K3: convM ∥ topk_s2
    k3_convM_s2<<<1152, blk, 0, stream>>>(W, mb);

    // stage-4 gathered patch-GEMM + fused combine -> agg half of cat2T
    patch_kernel<<<1024, blk, 0, stream>>>(W, OFF_CATT, OFF_IDX, OFF_ZROW, OFF_WB,
                                           (const float*)(W + OFF_MASK), nnb,
                                           (ushort*)(W + OFF_CAT2T));

    // final conv on concat(agg, ref) -> NCHW fp32 d_out (float4 stores)
    convA_kernel<<<1024, blk, 0, stream>>>(W, ab, out);
}